// Round 2
// baseline (2255.905 us; speedup 1.0000x reference)
//
#include <hip/hip_runtime.h>
#include <hip/hip_fp16.h>

#define Tn 1024
#define NB 128

typedef _Float16 h2_t __attribute__((ext_vector_type(2)));

__device__ __forceinline__ float dot2f(h2_t a, h2_t b, float c) {
#if __has_builtin(__builtin_amdgcn_fdot2)
  return __builtin_amdgcn_fdot2(a, b, c, false);
#else
  return c + (float)a[0] * (float)b[0] + (float)a[1] * (float)b[1];
#endif
}

__device__ __forceinline__ h2_t u2h(unsigned u) {
  union { unsigned u; h2_t h; } c; c.u = u; return c.h;
}

// quad_perm DPP xor-adds (VALU pipe, keeps the reduce off the LDS pipe)
__device__ __forceinline__ float dpp_xor1(float v) {
  int i = __builtin_bit_cast(int, v);
  return __builtin_bit_cast(float, __builtin_amdgcn_update_dpp(i, i, 0xB1, 0xF, 0xF, true));
}
__device__ __forceinline__ float dpp_xor2(float v) {
  int i = __builtin_bit_cast(int, v);
  return __builtin_bit_cast(float, __builtin_amdgcn_update_dpp(i, i, 0x4E, 0xF, 0xF, true));
}

// ---- Phase 1: gv[d][v][row] = emb[v] . w_ih_d[row] + b_ih_d[row]  (row in [0,768))
__global__ __launch_bounds__(768)
void gv_build(const float* __restrict__ emb,
              const float* __restrict__ wihf, const float* __restrict__ bihf,
              const float* __restrict__ wihb, const float* __restrict__ bihb,
              float* __restrict__ gv)
{
  const int d  = blockIdx.x >> 7;
  const int v4 = (blockIdx.x & 127) * 4;
  const float* wih = d ? wihb : wihf;
  const float* bih = d ? bihb : bihf;
  __shared__ float se[4][128];
  const int tid = threadIdx.x;
  if (tid < 512) se[tid >> 7][tid & 127] = emb[(v4 + (tid >> 7)) * 128 + (tid & 127)];
  __syncthreads();
  const int row = tid;
  const float b0 = bih[row];
  float a0 = b0, a1 = b0, a2 = b0, a3 = b0;
  #pragma unroll
  for (int e = 0; e < 128; e += 4) {
    const float4 w = *reinterpret_cast<const float4*>(&wih[row * 128 + e]);
    a0 = fmaf(w.x, se[0][e], a0); a0 = fmaf(w.y, se[0][e+1], a0);
    a0 = fmaf(w.z, se[0][e+2], a0); a0 = fmaf(w.w, se[0][e+3], a0);
    a1 = fmaf(w.x, se[1][e], a1); a1 = fmaf(w.y, se[1][e+1], a1);
    a1 = fmaf(w.z, se[1][e+2], a1); a1 = fmaf(w.w, se[1][e+3], a1);
    a2 = fmaf(w.x, se[2][e], a2); a2 = fmaf(w.y, se[2][e+1], a2);
    a2 = fmaf(w.z, se[2][e+2], a2); a2 = fmaf(w.w, se[2][e+3], a2);
    a3 = fmaf(w.x, se[3][e], a3); a3 = fmaf(w.y, se[3][e+1], a3);
    a3 = fmaf(w.z, se[3][e+2], a3); a3 = fmaf(w.w, se[3][e+3], a3);
  }
  float* out = gv + (size_t)(d * 512 + v4) * 768 + row;
  out[0] = a0; out[768] = a1; out[1536] = a2; out[2304] = a3;
}

// ---- Phase 2: per-(batch,dir) GRU scan.
// 1024 threads: thread = (row j = tid>>2, k-quarter q = tid&3).
// Weights: 96 h2 regs/thread (fits VGPR budget at 4 waves/SIMD -> no AGPR moves).
// h in LDS, quarter-partitioned with 16B stagger (q*144B) -> conflict-free b128 reads.
__global__ __launch_bounds__(1024)
void gru_scan(const int* __restrict__ x,
              const float* __restrict__ gv,
              const float* __restrict__ whhf,
              const float* __restrict__ whhb,
              const float* __restrict__ bhhf,
              const float* __restrict__ bhhb,
              const float* __restrict__ fcw,
              float* __restrict__ em)
{
  const int tid = threadIdx.x;
  const int j   = tid >> 2;   // hidden unit 0..255
  const int q   = tid & 3;    // k-quarter
  const int dir = blockIdx.x & 1;
  const int b   = blockIdx.x >> 1;

  const float* whh = dir ? whhb : whhf;
  const float* bhh = dir ? bhhb : bhhf;

  __shared__ float wstage[128][260];            // 133,120 B staging
  __shared__ __align__(16) char hb[2 * 576];    // double-buffered h, staggered quarters
  __shared__ __align__(16) h2_t fcs[4][132];    // fc weights (dir slice), f16 pairs

  // fc weights + h init
  if (tid < 512) {
    const int l = tid >> 7, c = tid & 127;
    h2_t f;
    f[0] = (_Float16)fcw[l * 512 + dir * 256 + 2 * c];
    f[1] = (_Float16)fcw[l * 512 + dir * 256 + 2 * c + 1];
    fcs[l][c] = f;
  }
  if (tid < 72) *reinterpret_cast<uint4*>(hb + tid * 16) = make_uint4(0, 0, 0, 0);

  // Stage w_hh through LDS in 128-row chunks, convert to f16 register tiles.
  // w[g*32+kk] = w_hh[g*256+j][q*64 + 2kk .. +1]
  h2_t w[96];
  for (int ch = 0; ch < 6; ++ch) {
    const int r0 = ch << 7;
    #pragma unroll
    for (int i = 0; i < 8; ++i) {
      const int f  = i * 1024 + tid;     // float4 index
      const int rr = f >> 6;             // 64 float4 per 256-col row
      const int cc = (f & 63) << 2;
      *reinterpret_cast<float4*>(&wstage[rr][cc]) =
          *reinterpret_cast<const float4*>(&whh[(size_t)(r0 + rr) * 256 + cc]);
    }
    __syncthreads();
    #pragma unroll
    for (int g = 0; g < 3; ++g) {
      const int row = (g << 8) + j;
      if (row >= r0 && row < r0 + 128) {
        const float* src = &wstage[row - r0][q << 6];
        #pragma unroll
        for (int kk = 0; kk < 32; ++kk) {
          const float2 wv = *reinterpret_cast<const float2*>(src + 2 * kk);
          h2_t ww; ww[0] = (_Float16)wv.x; ww[1] = (_Float16)wv.y;
          w[(g << 5) + kk] = ww;
        }
      }
    }
    __syncthreads();
  }

  float br = 0.f, bz = 0.f, bn = 0.f, ho = 0.f;
  if (q == 0) { br = bhh[j]; bz = bhh[j + 256]; bn = bhh[j + 512]; }

  const float* gvd  = gv + (size_t)dir * (512 * 768);
  const int*   xb   = x + b * Tn;
  float*       emo  = em + (size_t)(dir * NB + b) * (Tn * 4);
  const int    wv_id = tid >> 6;
  const int    el    = tid & 3;
  const int    ec    = (tid >> 2) & 15;
  const int    hq_off = q * 144;
  const int    hw_off = (j >> 6) * 144 + (j & 63) * 2;

  for (int step = 0; step < Tn; ++step) {
    const int cur = step & 1;
    const int tt  = dir ? (Tn - 1 - step) : step;
    const int tok = xb[tt];

    float gir = 0.f, giz = 0.f, gin = 0.f;
    if (q == 0) {
      const float* g = gvd + tok * 768 + j;
      gir = g[0]; giz = g[256]; gin = g[512];
    }

    // Emission for previous step's h (rotates across the 16 waves).
    if (wv_id == (step & 15) && step > 0) {
      const int ptt = dir ? (Tn - step) : (step - 1);
      const char* hp = hb + cur * 576 + (ec >> 2) * 144 + (ec & 3) * 32;
      const uint4 hA = *reinterpret_cast<const uint4*>(hp);
      const uint4 hB = *reinterpret_cast<const uint4*>(hp + 16);
      const uint4 fA = *reinterpret_cast<const uint4*>(&fcs[el][ec * 8]);
      const uint4 fB = *reinterpret_cast<const uint4*>(&fcs[el][ec * 8 + 4]);
      float acc = 0.f;
      acc = dot2f(u2h(fA.x), u2h(hA.x), acc);
      acc = dot2f(u2h(fA.y), u2h(hA.y), acc);
      acc = dot2f(u2h(fA.z), u2h(hA.z), acc);
      acc = dot2f(u2h(fA.w), u2h(hA.w), acc);
      acc = dot2f(u2h(fB.x), u2h(hB.x), acc);
      acc = dot2f(u2h(fB.y), u2h(hB.y), acc);
      acc = dot2f(u2h(fB.z), u2h(hB.z), acc);
      acc = dot2f(u2h(fB.w), u2h(hB.w), acc);
      acc += __shfl_xor(acc, 4);
      acc += __shfl_xor(acc, 8);
      acc += __shfl_xor(acc, 16);
      acc += __shfl_xor(acc, 32);
      if (ec == 0) emo[ptt * 4 + el] = acc;
    }

    // Recurrent dots: 3 gates x 64 k per thread.
    float dr = 0.f, dz = 0.f, dn = 0.f;
    const char* hbase = hb + cur * 576 + hq_off;
    #pragma unroll
    for (int c = 0; c < 8; ++c) {
      const uint4 hq = *reinterpret_cast<const uint4*>(hbase + c * 16);
      const h2_t h0 = u2h(hq.x), h1 = u2h(hq.y), h2v = u2h(hq.z), h3 = u2h(hq.w);
      dr = dot2f(w[4*c+0], h0, dr);  dz = dot2f(w[32+4*c+0], h0, dz);  dn = dot2f(w[64+4*c+0], h0, dn);
      dr = dot2f(w[4*c+1], h1, dr);  dz = dot2f(w[32+4*c+1], h1, dz);  dn = dot2f(w[64+4*c+1], h1, dn);
      dr = dot2f(w[4*c+2], h2v, dr); dz = dot2f(w[32+4*c+2], h2v, dz); dn = dot2f(w[64+4*c+2], h2v, dn);
      dr = dot2f(w[4*c+3], h3, dr);  dz = dot2f(w[32+4*c+3], h3, dz);  dn = dot2f(w[64+4*c+3], h3, dn);
    }

    // Quad combine on the VALU pipe (DPP), all lanes get full sums.
    dr += dpp_xor1(dr); dr += dpp_xor2(dr);
    dz += dpp_xor1(dz); dz += dpp_xor2(dz);
    dn += dpp_xor1(dn); dn += dpp_xor2(dn);

    if (q == 0) {
      const float r    = 1.f / (1.f + __expf(-(gir + dr + br)));
      const float z    = 1.f / (1.f + __expf(-(giz + dz + bz)));
      const float npre = gin + r * (dn + bn);
      const float e2   = __expf(-2.f * npre);
      const float n    = (1.f - e2) / (1.f + e2);
      const float hnew = (1.f - z) * n + z * ho;
      ho = hnew;
      *reinterpret_cast<_Float16*>(hb + (cur ^ 1) * 576 + hw_off) = (_Float16)hnew;
    }
    __syncthreads();
  }

  // Emission for the final step's h.
  if (wv_id == 0) {
    const int ptt = dir ? 0 : (Tn - 1);
    const char* hp = hb + (Tn & 1) * 576 + (ec >> 2) * 144 + (ec & 3) * 32;
    const uint4 hA = *reinterpret_cast<const uint4*>(hp);
    const uint4 hB = *reinterpret_cast<const uint4*>(hp + 16);
    const uint4 fA = *reinterpret_cast<const uint4*>(&fcs[el][ec * 8]);
    const uint4 fB = *reinterpret_cast<const uint4*>(&fcs[el][ec * 8 + 4]);
    float acc = 0.f;
    acc = dot2f(u2h(fA.x), u2h(hA.x), acc);
    acc = dot2f(u2h(fA.y), u2h(hA.y), acc);
    acc = dot2f(u2h(fA.z), u2h(hA.z), acc);
    acc = dot2f(u2h(fA.w), u2h(hA.w), acc);
    acc = dot2f(u2h(fB.x), u2h(hB.x), acc);
    acc = dot2f(u2h(fB.y), u2h(hB.y), acc);
    acc = dot2f(u2h(fB.z), u2h(hB.z), acc);
    acc = dot2f(u2h(fB.w), u2h(hB.w), acc);
    acc += __shfl_xor(acc, 4);
    acc += __shfl_xor(acc, 8);
    acc += __shfl_xor(acc, 16);
    acc += __shfl_xor(acc, 32);
    if (ec == 0) emo[ptt * 4 + el] = acc;
  }
}

// ---- Phase 3: CRF negative log-likelihood per batch (4 lanes per batch element)
__global__ __launch_bounds__(64)
void crf_nllh(const int* __restrict__ tags,
              const float* __restrict__ em,
              const float* __restrict__ fc_b,
              const float* __restrict__ st,
              const float* __restrict__ et,
              const float* __restrict__ tr,
              float* __restrict__ llh)
{
  const int lane = threadIdx.x;
  const int l = lane & 3;
  const int q = lane >> 2;
  const int b = blockIdx.x * 16 + q;
  const float* ef = em + (size_t)b * Tn * 4;
  const float* eb = em + ((size_t)NB + b) * Tn * 4;
  const int* tg = tags + b * Tn;
  const float fcb = fc_b[l];
  const float tc0 = tr[l * 4 + l];
  const float tc1 = tr[(l ^ 1) * 4 + l];
  const float tc2 = tr[(l ^ 2) * 4 + l];
  const float tc3 = tr[(l ^ 3) * 4 + l];

  const float e0 = ef[l] + eb[l] + fcb;
  float alpha = st[l] + e0;
  int tprev = tg[0];
  float score = (tprev == l) ? (st[l] + e0) : 0.f;

  #pragma unroll 8
  for (int t = 1; t < Tn; ++t) {
    const float e = ef[t * 4 + l] + eb[t * 4 + l] + fcb;
    const int tc = tg[t];
    if (tc == l) {
      const int s2 = tprev ^ l;
      const float tsel = (s2 & 1) ? ((s2 & 2) ? tc3 : tc1)
                                  : ((s2 & 2) ? tc2 : tc0);
      score += e + tsel;
    }
    tprev = tc;
    const float a1 = __shfl_xor(alpha, 1);
    const float a2 = __shfl_xor(alpha, 2);
    const float a3 = __shfl_xor(alpha, 3);
    const float v0 = alpha + tc0;
    const float v1 = a1 + tc1;
    const float v2 = a2 + tc2;
    const float v3 = a3 + tc3;
    const float mx = fmaxf(fmaxf(v0, v1), fmaxf(v2, v3));
    const float s = __expf(v0 - mx) + __expf(v1 - mx) + __expf(v2 - mx) + __expf(v3 - mx);
    alpha = mx + __logf(s) + e;
  }

  score += (tprev == l) ? et[l] : 0.f;
  float ae = alpha + et[l];
  float m1 = fmaxf(ae, __shfl_xor(ae, 1));
  m1 = fmaxf(m1, __shfl_xor(m1, 2));
  float se = __expf(ae - m1);
  se += __shfl_xor(se, 1);
  se += __shfl_xor(se, 2);
  const float logZ = m1 + __logf(se);
  float sc = score + __shfl_xor(score, 1);
  sc += __shfl_xor(sc, 2);
  if (l == 0) llh[b] = sc - logZ;
}

// ---- Phase 4: out = -mean(llh)
__global__ __launch_bounds__(128)
void reduce_mean(const float* __restrict__ llh, float* __restrict__ out)
{
  const int t = threadIdx.x;
  float v = llh[t];
  #pragma unroll
  for (int m = 32; m >= 1; m >>= 1) v += __shfl_xor(v, m);
  __shared__ float s2[2];
  if ((t & 63) == 0) s2[t >> 6] = v;
  __syncthreads();
  if (t == 0) out[0] = -(s2[0] + s2[1]) * (1.f / 128.f);
}

extern "C" void kernel_launch(void* const* d_in, const int* in_sizes, int n_in,
                              void* d_out, int out_size, void* d_ws, size_t ws_size,
                              hipStream_t stream) {
  const int*   x    = (const int*)d_in[0];
  const int*   tags = (const int*)d_in[1];
  // d_in[2] = mask (all ones) -- unused
  const float* emb  = (const float*)d_in[3];
  const float* wihf = (const float*)d_in[4];
  const float* whhf = (const float*)d_in[5];
  const float* bihf = (const float*)d_in[6];
  const float* bhhf = (const float*)d_in[7];
  const float* wihb = (const float*)d_in[8];
  const float* whhb = (const float*)d_in[9];
  const float* bihb = (const float*)d_in[10];
  const float* bhhb = (const float*)d_in[11];
  const float* fcw  = (const float*)d_in[12];
  const float* fcb  = (const float*)d_in[13];
  const float* st   = (const float*)d_in[14];
  const float* et   = (const float*)d_in[15];
  const float* tr   = (const float*)d_in[16];

  char* ws = (char*)d_ws;
  float* gv  = (float*)ws;                          // 2*512*768*4   = 3,145,728 B
  float* em  = (float*)(ws + 3145728);              // 2*128*1024*4*4 = 4,194,304 B
  float* llh = (float*)(ws + 3145728 + 4194304);    // 512 B

  gv_build<<<dim3(256), dim3(768), 0, stream>>>(emb, wihf, bihf, wihb, bihb, gv);
  gru_scan<<<dim3(256), dim3(1024), 0, stream>>>(x, gv, whhf, whhb, bhhf, bhhb, fcw, em);
  crf_nllh<<<dim3(8), dim3(64), 0, stream>>>(tags, em, fcb, st, et, tr, llh);
  reduce_mean<<<dim3(1), dim3(128), 0, stream>>>(llh, (float*)d_out);
}